// Round 9
// baseline (695.829 us; speedup 1.0000x reference)
//
#include <hip/hip_runtime.h>
#include <math.h>

// ---------------------------------------------------------------------------
// AGNNet: GAT-like 3-layer GNN. N=100000 nodes, E=800000 edges, HID=64.
// R9 = R8 with the CSR build rebuilt around ZERO global atomics (R7/R8
// counters proved device-scope atomics write through the fabric ~32B each:
// WRITE_SIZE identical with/without XCD partitioning).
//  - degree: 4 chunks x 32 partitions, LDS histograms -> exclusive partials
//    (plain stores); runs inside the in_gemm megakernel (hidden).
//  - rowptr: scan sums the 4 partials inline (exact int math).
//  - place: LDS cursor = rowptr + prefix(partials)  (stable chunk offsets),
//    LDS-atomic slot, plain stores, partition region single-XCD (bid%8==p%8).
//  - sortrow: XCD-aligned 2 blocks/partition, rows sorted by edge id
//    -> CSR content bit-identical to R8 -> absmax unchanged (9.765625e-4).
// All float kernels byte-identical to R8 (numeric order preserved).
// ---------------------------------------------------------------------------

#define HID 64
#define INC 128
#define NPART 32
#define NCHUNK 4
#define MAXP 3456      // max nodes per partition supported (N<=110592)

// ---------------- Megakernel: partitioned LDS degree (bid<128) || in_gemm --
__global__ __launch_bounds__(256) void k_ingemm_deg(
    const float* __restrict__ x, const float* __restrict__ Win,
    const float* __restrict__ bin, const float* __restrict__ wp,
    const float* __restrict__ attw,
    float* __restrict__ h0, float* __restrict__ delta, float* __restrict__ hwp,
    float* __restrict__ ai, float* __restrict__ aj, int n,
    const int* __restrict__ dst, int* __restrict__ partials, int E, int psize)
{
    __shared__ float xs[64 * 68];     // 17.4 KB (deg branch aliases as hist)
    __shared__ float Ws[64 * 64];     // 16 KB (one K-chunk)
    const int t = threadIdx.x;
    const int bid = blockIdx.x;

    if (bid < NPART * NCHUNK) {
        // ---- degree branch: LDS histogram, exclusive partial write ----
        int* hist = (int*)xs;
        const int p  = bid & (NPART - 1);
        const int c  = bid / NPART;
        const int lo = p * psize;
        const int hi = min(lo + psize, n);
        const int cnt = hi - lo;
        for (int i = t; i < cnt; i += 256) hist[i] = 0;
        __syncthreads();
        const int Ec = (E + NCHUNK - 1) / NCHUNK;
        const int e0 = c * Ec;
        const int e1 = min(e0 + Ec, E);
        for (int e = e0 + t; e < e1; e += 256) {
            int d = dst[e];
            if (d >= lo && d < hi) atomicAdd(&hist[d - lo], 1);
        }
        __syncthreads();
        int* part = partials + (size_t)c * n;
        for (int i = t; i < cnt; i += 256) part[lo + i] = hist[i];
        return;
    }

    // ---- in_gemm branch (bit-exact R8): 64-node tile, K in 2x64 chunks ----
    const int node0 = (bid - NPART * NCHUNK) * 64;
    const int cx = t & 15;
    const int ny = t >> 4;

    float acc[4][4];
    const float4 bv = *(const float4*)&bin[cx * 4];
    #pragma unroll
    for (int i = 0; i < 4; ++i) {
        acc[i][0] = bv.x; acc[i][1] = bv.y; acc[i][2] = bv.z; acc[i][3] = bv.w;
    }

    #pragma unroll
    for (int ch = 0; ch < 2; ++ch) {
        if (ch) __syncthreads();
        #pragma unroll
        for (int p = 0; p < 4; ++p) {
            int c = t + p * 256;
            int row = c >> 4;
            int col = (c & 15) * 4;
            float4 v = make_float4(0.f, 0.f, 0.f, 0.f);
            if (node0 + row < n)
                v = *(const float4*)&x[(size_t)(node0 + row) * INC + ch * 64 + col];
            *(float4*)&xs[row * 68 + col] = v;
        }
        #pragma unroll
        for (int p = 0; p < 4; ++p) {
            int c = t + p * 256;
            *(float4*)&Ws[c * 4] = *(const float4*)&Win[(size_t)ch * 64 * HID + c * 4];
        }
        __syncthreads();

        #pragma unroll 4
        for (int k4 = 0; k4 < 16; ++k4) {
            float4 xv[4];
            #pragma unroll
            for (int i = 0; i < 4; ++i)
                xv[i] = *(const float4*)&xs[(i * 16 + ny) * 68 + k4 * 4];
            #pragma unroll
            for (int kk = 0; kk < 4; ++kk) {
                float4 w = *(const float4*)&Ws[(k4 * 4 + kk) * HID + cx * 4];
                #pragma unroll
                for (int i = 0; i < 4; ++i) {
                    float xval = reinterpret_cast<const float*>(&xv[i])[kk];
                    acc[i][0] = fmaf(xval, w.x, acc[i][0]);
                    acc[i][1] = fmaf(xval, w.y, acc[i][1]);
                    acc[i][2] = fmaf(xval, w.z, acc[i][2]);
                    acc[i][3] = fmaf(xval, w.w, acc[i][3]);
                }
            }
        }
    }

    const float4 wpv = *(const float4*)&wp[cx * 4];
    const float4 wiv = *(const float4*)&attw[cx * 4];
    const float4 wjv = *(const float4*)&attw[HID + cx * 4];

    #pragma unroll
    for (int i = 0; i < 4; ++i) {
        const int node = node0 + i * 16 + ny;
        float h0v = fmaxf(acc[i][0], 0.f);
        float h1v = fmaxf(acc[i][1], 0.f);
        float h2v = fmaxf(acc[i][2], 0.f);
        float h3v = fmaxf(acc[i][3], 0.f);
        if (node < n) {
            float4 hv = make_float4(h0v, h1v, h2v, h3v);
            *(float4*)&h0[(size_t)node * HID + cx * 4] = hv;
        }
        float vd = h0v + h1v + h2v + h3v;
        float vw = h0v * wpv.x + h1v * wpv.y + h2v * wpv.z + h3v * wpv.w;
        float vi = h0v * wiv.x + h1v * wiv.y + h2v * wiv.z + h3v * wiv.w;
        float vj = h0v * wjv.x + h1v * wjv.y + h2v * wjv.z + h3v * wjv.w;
        #pragma unroll
        for (int m = 1; m < 16; m <<= 1) {
            vd += __shfl_xor(vd, m);
            vw += __shfl_xor(vw, m);
            vi += __shfl_xor(vi, m);
            vj += __shfl_xor(vj, m);
        }
        if (cx == 0 && node < n) {
            delta[node] = vd; hwp[node] = vw; ai[node] = vi; aj[node] = vj;
        }
    }
}

// ---------------- CSR scans (deg = sum of 4 partials) ----------------
__global__ __launch_bounds__(256) void k_scan1(
    const int* __restrict__ partials, int* __restrict__ rowptr,
    int* __restrict__ bsum, int n)
{
    __shared__ int sdata[256];
    const int t = threadIdx.x;
    const int i0 = blockIdx.x * 1024 + t * 4;
    const int* p0 = partials;
    const int* p1 = partials + (size_t)n;
    const int* p2 = partials + (size_t)2 * n;
    const int* p3 = partials + (size_t)3 * n;
    int v[4];
    #pragma unroll
    for (int j = 0; j < 4; ++j) {
        int idx = i0 + j;
        v[j] = (idx < n) ? (p0[idx] + p1[idx] + p2[idx] + p3[idx]) : 0;
    }
    int ts = v[0] + v[1] + v[2] + v[3];
    sdata[t] = ts;
    __syncthreads();
    for (int off = 1; off < 256; off <<= 1) {
        int add = (t >= off) ? sdata[t - off] : 0;
        __syncthreads();
        sdata[t] += add;
        __syncthreads();
    }
    int excl = sdata[t] - ts;
    int run = excl;
    #pragma unroll
    for (int j = 0; j < 4; ++j) {
        if (i0 + j < n) rowptr[i0 + j] = run;
        run += v[j];
    }
    if (t == 255) bsum[blockIdx.x] = sdata[255];
}

__global__ __launch_bounds__(128) void k_scan2(int* __restrict__ bsum, int B)
{
    __shared__ int sdata[128];
    const int t = threadIdx.x;
    int v = (t < B) ? bsum[t] : 0;
    sdata[t] = v;
    __syncthreads();
    for (int off = 1; off < 128; off <<= 1) {
        int add = (t >= off) ? sdata[t - off] : 0;
        __syncthreads();
        sdata[t] += add;
        __syncthreads();
    }
    if (t < B) bsum[t] = sdata[t] - v;
}

__global__ __launch_bounds__(256) void k_scan3(
    int* __restrict__ rowptr, const int* __restrict__ bsum, int n, int E)
{
    const int t = threadIdx.x;
    const int i0 = blockIdx.x * 1024 + t * 4;
    const int add = bsum[blockIdx.x];
    #pragma unroll
    for (int j = 0; j < 4; ++j) {
        int i = i0 + j;
        if (i < n) rowptr[i] += add;
    }
    if (blockIdx.x == 0 && t == 0) rowptr[n] = E;
}

// ---------------- Place: LDS cursor, zero global atomics ----------------
// block (c,p): cursor = rowptr + sum of partials of chunks < c; scan chunk c.
// bid = c*NPART+p -> bid%8 == p%8: all chunks of a partition on one XCD.
__global__ __launch_bounds__(256) void k_place(
    const int* __restrict__ dst, const int* __restrict__ rowptr,
    const int* __restrict__ partials, int* __restrict__ csr_eid,
    int E, int n, int psize)
{
    __shared__ int cur[MAXP];
    const int t = threadIdx.x;
    const int p  = blockIdx.x & (NPART - 1);
    const int c  = blockIdx.x / NPART;
    const int lo = p * psize;
    const int hi = min(lo + psize, n);
    const int cnt = hi - lo;

    const int* p0 = partials;
    const int* p1 = partials + (size_t)n;
    const int* p2 = partials + (size_t)2 * n;
    for (int i = t; i < cnt; i += 256) {
        int base = rowptr[lo + i];
        if (c > 0) base += p0[lo + i];
        if (c > 1) base += p1[lo + i];
        if (c > 2) base += p2[lo + i];
        cur[i] = base;
    }
    __syncthreads();

    const int Ec = (E + NCHUNK - 1) / NCHUNK;
    const int e0 = c * Ec;
    const int e1 = min(e0 + Ec, E);
    for (int e = e0 + t; e < e1; e += 256) {
        int d = dst[e];
        if (d >= lo && d < hi) {
            int slot = atomicAdd(&cur[d - lo], 1);   // LDS atomic
            csr_eid[slot] = e;
        }
    }
}

// sort each row by edge id ascending (deterministic, reference order);
// 2 XCD-aligned blocks per partition (bid%8 == p%8, csr region L2-local).
__global__ __launch_bounds__(256) void k_sortrow(
    const int* __restrict__ rowptr, int* __restrict__ csr_eid,
    const int* __restrict__ src, int* __restrict__ csr_src,
    int n, int psize)
{
    const int t = threadIdx.x;
    const int p  = blockIdx.x & (NPART - 1);
    const int h  = blockIdx.x / NPART;
    const int lo = p * psize;
    const int hi = min(lo + psize, n);
    const int hs = (psize + 1) >> 1;
    const int start = lo + h * hs;
    const int end   = min(hi, start + hs);

    for (int r = start + t; r < end; r += 256) {
        const int p0 = rowptr[r], p1 = rowptr[r + 1];
        for (int a = p0 + 1; a < p1; ++a) {
            int key = csr_eid[a];
            int b = a - 1;
            while (b >= p0 && csr_eid[b] > key) {
                csr_eid[b + 1] = csr_eid[b];
                --b;
            }
            csr_eid[b + 1] = key;
        }
        for (int q = p0; q < p1; ++q) csr_src[q] = src[csr_eid[q]];
    }
}

// ---------------- Attention prep (R8 exact) ----------------
__global__ __launch_bounds__(256) void k_neigh_pi(
    const int* __restrict__ rowptr, const int* __restrict__ csr_src,
    const float* __restrict__ delta, const float* __restrict__ hwp,
    float* __restrict__ pi, int n)
{
    int i = blockIdx.x * 256 + threadIdx.x;
    if (i >= n) return;
    int p0 = rowptr[i], p1 = rowptr[i + 1];
    float s = 0.f;
    for (int p = p0; p < p1; ++p) s += delta[csr_src[p]];
    float v = hwp[i] + s;
    pi[i] = 1.f / (1.f + expf(-v));
}

__global__ __launch_bounds__(256) void k_att(
    const int* __restrict__ rowptr, const int* __restrict__ csr_src,
    const float* __restrict__ ai, const float* __restrict__ aj,
    const float* __restrict__ pi, const float* __restrict__ attw,
    const float* __restrict__ attb,
    float* __restrict__ alpha_csr, int n)
{
    int i = blockIdx.x * 256 + threadIdx.x;
    if (i >= n) return;
    const float wpe = attw[2 * HID];
    const float ab  = attb[0];
    int p0 = rowptr[i], p1 = rowptr[i + 1];
    float aid = ai[i];
    float den = 0.f;
    for (int p = p0; p < p1; ++p) {
        int s = csr_src[p];
        float v = aid + aj[s] + pi[s] * wpe + ab;
        v = v > 0.f ? v : 0.2f * v;
        float ev = expf(v);
        alpha_csr[p] = ev;
        den += ev;
    }
    float inv = 1.f / (den + 1e-16f);
    for (int p = p0; p < p1; ++p) alpha_csr[p] *= inv;
}

// ---------------- GEMM 64x64 (R8 exact) ----------------
__global__ __launch_bounds__(256) void k_gemm64(
    const float* __restrict__ hin, const float* __restrict__ W,
    const float* __restrict__ b, float* __restrict__ hout, int n, int relu_in)
{
    __shared__ float xs[64 * 68];
    __shared__ float Ws[HID * HID];
    const int t = threadIdx.x;
    const int node0 = blockIdx.x * 64;

    #pragma unroll
    for (int p = 0; p < 4; ++p) {
        int c = t + p * 256;
        *(float4*)&Ws[c * 4] = *(const float4*)&W[c * 4];
    }
    #pragma unroll
    for (int p = 0; p < 4; ++p) {
        int c = t + p * 256;
        int row = c >> 4;
        int col = (c & 15) * 4;
        float4 v = make_float4(0.f, 0.f, 0.f, 0.f);
        if (node0 + row < n) v = *(const float4*)&hin[(size_t)(node0 + row) * HID + col];
        if (relu_in) {
            v.x = fmaxf(v.x, 0.f); v.y = fmaxf(v.y, 0.f);
            v.z = fmaxf(v.z, 0.f); v.w = fmaxf(v.w, 0.f);
        }
        *(float4*)&xs[row * 68 + col] = v;
    }
    __syncthreads();

    const int cx = t & 15;
    const int ny = t >> 4;
    float acc[4][4];
    const float4 bv = *(const float4*)&b[cx * 4];
    #pragma unroll
    for (int i = 0; i < 4; ++i) {
        acc[i][0] = bv.x; acc[i][1] = bv.y; acc[i][2] = bv.z; acc[i][3] = bv.w;
    }

    #pragma unroll 4
    for (int k4 = 0; k4 < 16; ++k4) {
        float4 xv[4];
        #pragma unroll
        for (int i = 0; i < 4; ++i)
            xv[i] = *(const float4*)&xs[(i * 16 + ny) * 68 + k4 * 4];
        #pragma unroll
        for (int kk = 0; kk < 4; ++kk) {
            float4 w = *(const float4*)&Ws[(k4 * 4 + kk) * HID + cx * 4];
            #pragma unroll
            for (int i = 0; i < 4; ++i) {
                float xval = reinterpret_cast<const float*>(&xv[i])[kk];
                acc[i][0] = fmaf(xval, w.x, acc[i][0]);
                acc[i][1] = fmaf(xval, w.y, acc[i][1]);
                acc[i][2] = fmaf(xval, w.z, acc[i][2]);
                acc[i][3] = fmaf(xval, w.w, acc[i][3]);
            }
        }
    }

    #pragma unroll
    for (int i = 0; i < 4; ++i) {
        const int node = node0 + i * 16 + ny;
        if (node < n) {
            float4 hv = make_float4(acc[i][0], acc[i][1], acc[i][2], acc[i][3]);
            *(float4*)&hout[(size_t)node * HID + cx * 4] = hv;
        }
    }
}

// ---------------- Gather (R8 exact): out[d] = Sum alpha * hl[src] ---------
__global__ __launch_bounds__(256) void k_gather(
    const int* __restrict__ rowptr, const int* __restrict__ csr_src,
    const float* __restrict__ alpha_csr, const float* __restrict__ hl,
    float* __restrict__ out, int n)
{
    const int wave = threadIdx.x >> 6;
    const int lane = threadIdx.x & 63;
    const int g    = lane >> 4;
    const int q    = lane & 15;
    const int node = blockIdx.x * 4 + wave;
    if (node >= n) return;

    const int p0 = rowptr[node], p1 = rowptr[node + 1];
    float4 acc = make_float4(0.f, 0.f, 0.f, 0.f);

    for (int base = p0; base < p1; base += 64) {
        int m = p1 - base; if (m > 64) m = 64;
        float a_l = 0.f; int s_l = 0;
        if (lane < m) { a_l = alpha_csr[base + lane]; s_l = csr_src[base + lane]; }
        for (int j = 0; j < m; j += 4) {
            const int e = j + g;
            float a = __shfl(a_l, e);
            int   s = __shfl(s_l, e);
            if (e < m) {
                float4 v = *(const float4*)&hl[(size_t)s * HID + q * 4];
                acc.x = fmaf(a, v.x, acc.x);
                acc.y = fmaf(a, v.y, acc.y);
                acc.z = fmaf(a, v.z, acc.z);
                acc.w = fmaf(a, v.w, acc.w);
            }
        }
    }
    #pragma unroll
    for (int m2 = 16; m2 <= 32; m2 <<= 1) {
        acc.x += __shfl_xor(acc.x, m2);
        acc.y += __shfl_xor(acc.y, m2);
        acc.z += __shfl_xor(acc.z, m2);
        acc.w += __shfl_xor(acc.w, m2);
    }
    if (g == 0)
        *(float4*)&out[(size_t)node * HID + q * 4] = acc;
}

// ---------------- Output GEMM 64x40 (R8 exact) ----------------
__global__ __launch_bounds__(256) void k_out_gemm(
    const float* __restrict__ hin, const float* __restrict__ W,
    const float* __restrict__ b, float* __restrict__ out, int n)
{
    __shared__ float xs[128 * 68];
    __shared__ float Ws[HID * 40];
    const int t = threadIdx.x;
    const int node0 = blockIdx.x * 128;

    #pragma unroll
    for (int p = 0; p < 3; ++p) {
        int c = t + p * 256;
        if (c < 640) *(float4*)&Ws[c * 4] = *(const float4*)&W[c * 4];
    }
    #pragma unroll
    for (int p = 0; p < 8; ++p) {
        int c = t + p * 256;
        int row = c >> 4;
        int col = (c & 15) * 4;
        float4 v = make_float4(0.f, 0.f, 0.f, 0.f);
        if (node0 + row < n) v = *(const float4*)&hin[(size_t)(node0 + row) * HID + col];
        v.x = fmaxf(v.x, 0.f); v.y = fmaxf(v.y, 0.f);
        v.z = fmaxf(v.z, 0.f); v.w = fmaxf(v.w, 0.f);
        *(float4*)&xs[row * 68 + col] = v;
    }
    __syncthreads();

    const int cx = t & 7;
    const int ny = t >> 3;
    float acc[4][5];
    #pragma unroll
    for (int j = 0; j < 5; ++j) {
        float bj = b[5 * cx + j];
        #pragma unroll
        for (int i = 0; i < 4; ++i) acc[i][j] = bj;
    }

    #pragma unroll 4
    for (int k4 = 0; k4 < 16; ++k4) {
        float4 xv[4];
        #pragma unroll
        for (int i = 0; i < 4; ++i)
            xv[i] = *(const float4*)&xs[(i * 32 + ny) * 68 + k4 * 4];
        #pragma unroll
        for (int kk = 0; kk < 4; ++kk) {
            int k = k4 * 4 + kk;
            float w[5];
            #pragma unroll
            for (int j = 0; j < 5; ++j) w[j] = Ws[k * 40 + 5 * cx + j];
            #pragma unroll
            for (int i = 0; i < 4; ++i) {
                float xval = reinterpret_cast<const float*>(&xv[i])[kk];
                #pragma unroll
                for (int j = 0; j < 5; ++j)
                    acc[i][j] = fmaf(xval, w[j], acc[i][j]);
            }
        }
    }

    #pragma unroll
    for (int i = 0; i < 4; ++i) {
        const int node = node0 + i * 32 + ny;
        if (node < n) {
            #pragma unroll
            for (int j = 0; j < 5; ++j)
                out[(size_t)node * 40 + 5 * cx + j] = acc[i][j];
        }
    }
}

extern "C" void kernel_launch(void* const* d_in, const int* in_sizes, int n_in,
                              void* d_out, int out_size, void* d_ws, size_t ws_size,
                              hipStream_t stream) {
    const float* x    = (const float*)d_in[0];
    const int*   ei   = (const int*)d_in[1];
    const float* Win  = (const float*)d_in[2];
    const float* bin  = (const float*)d_in[3];
    const float* wp   = (const float*)d_in[4];
    const float* attw = (const float*)d_in[5];
    const float* attb = (const float*)d_in[6];
    const float* Wout = (const float*)d_in[7];
    const float* bout = (const float*)d_in[8];
    const float* W0   = (const float*)d_in[9];
    const float* b0   = (const float*)d_in[10];
    const float* W1   = (const float*)d_in[11];
    const float* b1   = (const float*)d_in[12];
    const float* W2   = (const float*)d_in[13];
    const float* b2   = (const float*)d_in[14];

    const int N = in_sizes[0] / INC;
    const int E = in_sizes[1] / 2;
    const int* src = ei;
    const int* dst = ei + E;
    float* out = (float*)d_out;

    char* ws = (char*)d_ws;
    size_t off = 0;
    auto alloc = [&](size_t bytes) -> void* {
        void* p = ws + off;
        off = (off + bytes + 255) & ~(size_t)255;
        return p;
    };
    float* A        = (float*)alloc((size_t)N * HID * 4);
    float* Bf       = (float*)alloc((size_t)N * HID * 4);
    float* C        = (float*)alloc((size_t)N * HID * 4);
    float* delta    = (float*)alloc((size_t)N * 4);
    float* hwp      = (float*)alloc((size_t)N * 4);
    float* ai       = (float*)alloc((size_t)N * 4);
    float* aj       = (float*)alloc((size_t)N * 4);
    float* pi       = (float*)alloc((size_t)N * 4);
    int*   partials = (int*)alloc((size_t)NCHUNK * N * 4);
    int*   rowptr   = (int*)alloc((size_t)(N + 1) * 4);
    int*   bsum     = (int*)alloc(256 * 4);
    int*   csr_eid  = (int*)alloc((size_t)E * 4);
    int*   csr_src  = (int*)alloc((size_t)E * 4);
    float* alpha    = (float*)alloc((size_t)E * 4);

    const int tileBlocks64  = (N + 63) / 64;          // 1563
    const int tileBlocks128 = (N + 127) / 128;
    const int nodeBlocks256 = (N + 255) / 256;
    const int nodeBlocksW   = (N + 3) / 4;
    const int scanBlocks    = (N + 1023) / 1024;      // 98

    const int psize = (N + NPART - 1) / NPART;        // 3125 (<= MAXP)
    const int fusedBlocks = NPART * NCHUNK + tileBlocks64;

    // ---- megakernel: LDS-histogram degree (128 blocks) || in_gemm ----
    k_ingemm_deg<<<fusedBlocks, 256, 0, stream>>>(
        x, Win, bin, wp, attw, A, delta, hwp, ai, aj, N,
        dst, partials, E, psize);

    // ---- rowptr scans (deg = sum partials, exact) ----
    k_scan1<<<scanBlocks, 256, 0, stream>>>(partials, rowptr, bsum, N);
    k_scan2<<<1, 128, 0, stream>>>(bsum, scanBlocks);
    k_scan3<<<scanBlocks, 256, 0, stream>>>(rowptr, bsum, N, E);

    // ---- place (LDS cursor, no global atomics) + row sort ----
    k_place<<<NPART * NCHUNK, 256, 0, stream>>>(dst, rowptr, partials,
                                                csr_eid, E, N, psize);
    k_sortrow<<<NPART * 2, 256, 0, stream>>>(rowptr, csr_eid, src, csr_src,
                                             N, psize);

    // ---- attention ----
    k_neigh_pi<<<nodeBlocks256, 256, 0, stream>>>(rowptr, csr_src, delta, hwp, pi, N);
    k_att<<<nodeBlocks256, 256, 0, stream>>>(rowptr, csr_src, ai, aj, pi,
                                             attw, attb, alpha, N);

    // ---- layers (R8 exact) ----
    k_gemm64<<<tileBlocks64, 256, 0, stream>>>(A, W0, b0, Bf, N, 0);
    k_gather<<<nodeBlocksW, 256, 0, stream>>>(rowptr, csr_src, alpha, Bf, C, N);

    k_gemm64<<<tileBlocks64, 256, 0, stream>>>(C, W1, b1, A, N, 1);
    k_gather<<<nodeBlocksW, 256, 0, stream>>>(rowptr, csr_src, alpha, A, Bf, N);

    k_gemm64<<<tileBlocks64, 256, 0, stream>>>(Bf, W2, b2, C, N, 1);
    k_gather<<<nodeBlocksW, 256, 0, stream>>>(rowptr, csr_src, alpha, C, A, N);

    k_out_gemm<<<tileBlocks128, 256, 0, stream>>>(A, Wout, bout, out, N);
}

// Round 10
// 378.802 us; speedup vs baseline: 1.8369x; 1.8369x over previous
//
#include <hip/hip_runtime.h>
#include <math.h>

// ---------------------------------------------------------------------------
// AGNNet: GAT-like 3-layer GNN. N=100000 nodes, E=800000 edges, HID=64.
// R10 = R9's zero-global-atomic CSR build with the parallelism fixed:
//  - NCHUNK=16 x NPART=32 -> 512 degree blocks / 512 place blocks
//    (R9's 128 blocks x 781 iters was the 327us tail; now 195 iters, 2/CU)
//  - k_chunkprefix: exclusive prefix of partials across chunks (thread/node)
//    -> place cursor init = rowptr + partials[c] (one add), scan reads degtotal
//  - all float kernels byte-identical to R8/R9 (absmax stays 9.765625e-4)
// ---------------------------------------------------------------------------

#define HID 64
#define INC 128
#define NPART 32
#define NCHUNK 16
#define MAXP 3456      // max nodes per partition supported (N<=110592)

// ---------------- Megakernel: partitioned LDS degree (bid<512) || in_gemm --
__global__ __launch_bounds__(256) void k_ingemm_deg(
    const float* __restrict__ x, const float* __restrict__ Win,
    const float* __restrict__ bin, const float* __restrict__ wp,
    const float* __restrict__ attw,
    float* __restrict__ h0, float* __restrict__ delta, float* __restrict__ hwp,
    float* __restrict__ ai, float* __restrict__ aj, int n,
    const int* __restrict__ dst, int* __restrict__ partials, int E, int psize)
{
    __shared__ float xs[64 * 68];     // 17.4 KB (deg branch aliases as hist)
    __shared__ float Ws[64 * 64];     // 16 KB (one K-chunk)
    const int t = threadIdx.x;
    const int bid = blockIdx.x;

    if (bid < NPART * NCHUNK) {
        // ---- degree branch: LDS histogram, partial write (plain stores) ----
        int* hist = (int*)xs;
        const int p  = bid & (NPART - 1);
        const int c  = bid / NPART;
        const int lo = p * psize;
        const int hi = min(lo + psize, n);
        const int cnt = hi - lo;
        for (int i = t; i < cnt; i += 256) hist[i] = 0;
        __syncthreads();
        const int Ec = (E + NCHUNK - 1) / NCHUNK;
        const int e0 = c * Ec;
        const int e1 = min(e0 + Ec, E);
        for (int e = e0 + t; e < e1; e += 256) {
            int d = dst[e];
            if (d >= lo && d < hi) atomicAdd(&hist[d - lo], 1);
        }
        __syncthreads();
        int* part = partials + (size_t)c * n;
        for (int i = t; i < cnt; i += 256) part[lo + i] = hist[i];
        return;
    }

    // ---- in_gemm branch (bit-exact R8): 64-node tile, K in 2x64 chunks ----
    const int node0 = (bid - NPART * NCHUNK) * 64;
    const int cx = t & 15;
    const int ny = t >> 4;

    float acc[4][4];
    const float4 bv = *(const float4*)&bin[cx * 4];
    #pragma unroll
    for (int i = 0; i < 4; ++i) {
        acc[i][0] = bv.x; acc[i][1] = bv.y; acc[i][2] = bv.z; acc[i][3] = bv.w;
    }

    #pragma unroll
    for (int ch = 0; ch < 2; ++ch) {
        if (ch) __syncthreads();
        #pragma unroll
        for (int p = 0; p < 4; ++p) {
            int c = t + p * 256;
            int row = c >> 4;
            int col = (c & 15) * 4;
            float4 v = make_float4(0.f, 0.f, 0.f, 0.f);
            if (node0 + row < n)
                v = *(const float4*)&x[(size_t)(node0 + row) * INC + ch * 64 + col];
            *(float4*)&xs[row * 68 + col] = v;
        }
        #pragma unroll
        for (int p = 0; p < 4; ++p) {
            int c = t + p * 256;
            *(float4*)&Ws[c * 4] = *(const float4*)&Win[(size_t)ch * 64 * HID + c * 4];
        }
        __syncthreads();

        #pragma unroll 4
        for (int k4 = 0; k4 < 16; ++k4) {
            float4 xv[4];
            #pragma unroll
            for (int i = 0; i < 4; ++i)
                xv[i] = *(const float4*)&xs[(i * 16 + ny) * 68 + k4 * 4];
            #pragma unroll
            for (int kk = 0; kk < 4; ++kk) {
                float4 w = *(const float4*)&Ws[(k4 * 4 + kk) * HID + cx * 4];
                #pragma unroll
                for (int i = 0; i < 4; ++i) {
                    float xval = reinterpret_cast<const float*>(&xv[i])[kk];
                    acc[i][0] = fmaf(xval, w.x, acc[i][0]);
                    acc[i][1] = fmaf(xval, w.y, acc[i][1]);
                    acc[i][2] = fmaf(xval, w.z, acc[i][2]);
                    acc[i][3] = fmaf(xval, w.w, acc[i][3]);
                }
            }
        }
    }

    const float4 wpv = *(const float4*)&wp[cx * 4];
    const float4 wiv = *(const float4*)&attw[cx * 4];
    const float4 wjv = *(const float4*)&attw[HID + cx * 4];

    #pragma unroll
    for (int i = 0; i < 4; ++i) {
        const int node = node0 + i * 16 + ny;
        float h0v = fmaxf(acc[i][0], 0.f);
        float h1v = fmaxf(acc[i][1], 0.f);
        float h2v = fmaxf(acc[i][2], 0.f);
        float h3v = fmaxf(acc[i][3], 0.f);
        if (node < n) {
            float4 hv = make_float4(h0v, h1v, h2v, h3v);
            *(float4*)&h0[(size_t)node * HID + cx * 4] = hv;
        }
        float vd = h0v + h1v + h2v + h3v;
        float vw = h0v * wpv.x + h1v * wpv.y + h2v * wpv.z + h3v * wpv.w;
        float vi = h0v * wiv.x + h1v * wiv.y + h2v * wiv.z + h3v * wiv.w;
        float vj = h0v * wjv.x + h1v * wjv.y + h2v * wjv.z + h3v * wjv.w;
        #pragma unroll
        for (int m = 1; m < 16; m <<= 1) {
            vd += __shfl_xor(vd, m);
            vw += __shfl_xor(vw, m);
            vi += __shfl_xor(vi, m);
            vj += __shfl_xor(vj, m);
        }
        if (cx == 0 && node < n) {
            delta[node] = vd; hwp[node] = vw; ai[node] = vi; aj[node] = vj;
        }
    }
}

// ---------------- Chunk prefix: partials -> exclusive, degtotal ----------
__global__ __launch_bounds__(256) void k_chunkprefix(
    int* __restrict__ partials, int* __restrict__ degtotal, int n)
{
    int i = blockIdx.x * 256 + threadIdx.x;
    if (i >= n) return;
    int running = 0;
    #pragma unroll
    for (int c = 0; c < NCHUNK; ++c) {
        int v = partials[(size_t)c * n + i];
        partials[(size_t)c * n + i] = running;
        running += v;
    }
    degtotal[i] = running;
}

// ---------------- CSR scans ----------------
__global__ __launch_bounds__(256) void k_scan1(
    const int* __restrict__ degtotal, int* __restrict__ rowptr,
    int* __restrict__ bsum, int n)
{
    __shared__ int sdata[256];
    const int t = threadIdx.x;
    const int i0 = blockIdx.x * 1024 + t * 4;
    int v[4];
    #pragma unroll
    for (int j = 0; j < 4; ++j) v[j] = (i0 + j < n) ? degtotal[i0 + j] : 0;
    int ts = v[0] + v[1] + v[2] + v[3];
    sdata[t] = ts;
    __syncthreads();
    for (int off = 1; off < 256; off <<= 1) {
        int add = (t >= off) ? sdata[t - off] : 0;
        __syncthreads();
        sdata[t] += add;
        __syncthreads();
    }
    int excl = sdata[t] - ts;
    int run = excl;
    #pragma unroll
    for (int j = 0; j < 4; ++j) {
        if (i0 + j < n) rowptr[i0 + j] = run;
        run += v[j];
    }
    if (t == 255) bsum[blockIdx.x] = sdata[255];
}

__global__ __launch_bounds__(128) void k_scan2(int* __restrict__ bsum, int B)
{
    __shared__ int sdata[128];
    const int t = threadIdx.x;
    int v = (t < B) ? bsum[t] : 0;
    sdata[t] = v;
    __syncthreads();
    for (int off = 1; off < 128; off <<= 1) {
        int add = (t >= off) ? sdata[t - off] : 0;
        __syncthreads();
        sdata[t] += add;
        __syncthreads();
    }
    if (t < B) bsum[t] = sdata[t] - v;
}

__global__ __launch_bounds__(256) void k_scan3(
    int* __restrict__ rowptr, const int* __restrict__ bsum, int n, int E)
{
    const int t = threadIdx.x;
    const int i0 = blockIdx.x * 1024 + t * 4;
    const int add = bsum[blockIdx.x];
    #pragma unroll
    for (int j = 0; j < 4; ++j) {
        int i = i0 + j;
        if (i < n) rowptr[i] += add;
    }
    if (blockIdx.x == 0 && t == 0) rowptr[n] = E;
}

// ---------------- Place: LDS cursor, zero global atomics ----------------
// block (c,p): cursor[i] = rowptr[i] + partials[c][i] (exclusive prefix).
__global__ __launch_bounds__(256) void k_place(
    const int* __restrict__ dst, const int* __restrict__ rowptr,
    const int* __restrict__ partials, int* __restrict__ csr_eid,
    int E, int n, int psize)
{
    __shared__ int cur[MAXP];
    const int t = threadIdx.x;
    const int p  = blockIdx.x & (NPART - 1);
    const int c  = blockIdx.x / NPART;
    const int lo = p * psize;
    const int hi = min(lo + psize, n);
    const int cnt = hi - lo;

    const int* part = partials + (size_t)c * n;
    for (int i = t; i < cnt; i += 256)
        cur[i] = rowptr[lo + i] + part[lo + i];
    __syncthreads();

    const int Ec = (E + NCHUNK - 1) / NCHUNK;
    const int e0 = c * Ec;
    const int e1 = min(e0 + Ec, E);
    for (int e = e0 + t; e < e1; e += 256) {
        int d = dst[e];
        if (d >= lo && d < hi) {
            int slot = atomicAdd(&cur[d - lo], 1);   // LDS atomic
            csr_eid[slot] = e;
        }
    }
}

// sort each row by edge id ascending (deterministic, reference order);
// 8 blocks per partition for parallelism, XCD-aligned (bid%8 stable per p).
__global__ __launch_bounds__(256) void k_sortrow(
    const int* __restrict__ rowptr, int* __restrict__ csr_eid,
    const int* __restrict__ src, int* __restrict__ csr_src,
    int n, int psize)
{
    const int t = threadIdx.x;
    const int p  = blockIdx.x & (NPART - 1);
    const int h  = blockIdx.x / NPART;          // 0..7
    const int lo = p * psize;
    const int hi = min(lo + psize, n);
    const int hs = (psize + 7) >> 3;
    const int start = lo + h * hs;
    const int end   = min(hi, start + hs);

    for (int r = start + t; r < end; r += 256) {
        const int p0 = rowptr[r], p1 = rowptr[r + 1];
        for (int a = p0 + 1; a < p1; ++a) {
            int key = csr_eid[a];
            int b = a - 1;
            while (b >= p0 && csr_eid[b] > key) {
                csr_eid[b + 1] = csr_eid[b];
                --b;
            }
            csr_eid[b + 1] = key;
        }
        for (int q = p0; q < p1; ++q) csr_src[q] = src[csr_eid[q]];
    }
}

// ---------------- Attention prep (R8 exact) ----------------
__global__ __launch_bounds__(256) void k_neigh_pi(
    const int* __restrict__ rowptr, const int* __restrict__ csr_src,
    const float* __restrict__ delta, const float* __restrict__ hwp,
    float* __restrict__ pi, int n)
{
    int i = blockIdx.x * 256 + threadIdx.x;
    if (i >= n) return;
    int p0 = rowptr[i], p1 = rowptr[i + 1];
    float s = 0.f;
    for (int p = p0; p < p1; ++p) s += delta[csr_src[p]];
    float v = hwp[i] + s;
    pi[i] = 1.f / (1.f + expf(-v));
}

__global__ __launch_bounds__(256) void k_att(
    const int* __restrict__ rowptr, const int* __restrict__ csr_src,
    const float* __restrict__ ai, const float* __restrict__ aj,
    const float* __restrict__ pi, const float* __restrict__ attw,
    const float* __restrict__ attb,
    float* __restrict__ alpha_csr, int n)
{
    int i = blockIdx.x * 256 + threadIdx.x;
    if (i >= n) return;
    const float wpe = attw[2 * HID];
    const float ab  = attb[0];
    int p0 = rowptr[i], p1 = rowptr[i + 1];
    float aid = ai[i];
    float den = 0.f;
    for (int p = p0; p < p1; ++p) {
        int s = csr_src[p];
        float v = aid + aj[s] + pi[s] * wpe + ab;
        v = v > 0.f ? v : 0.2f * v;
        float ev = expf(v);
        alpha_csr[p] = ev;
        den += ev;
    }
    float inv = 1.f / (den + 1e-16f);
    for (int p = p0; p < p1; ++p) alpha_csr[p] *= inv;
}

// ---------------- GEMM 64x64 (R8 exact) ----------------
__global__ __launch_bounds__(256) void k_gemm64(
    const float* __restrict__ hin, const float* __restrict__ W,
    const float* __restrict__ b, float* __restrict__ hout, int n, int relu_in)
{
    __shared__ float xs[64 * 68];
    __shared__ float Ws[HID * HID];
    const int t = threadIdx.x;
    const int node0 = blockIdx.x * 64;

    #pragma unroll
    for (int p = 0; p < 4; ++p) {
        int c = t + p * 256;
        *(float4*)&Ws[c * 4] = *(const float4*)&W[c * 4];
    }
    #pragma unroll
    for (int p = 0; p < 4; ++p) {
        int c = t + p * 256;
        int row = c >> 4;
        int col = (c & 15) * 4;
        float4 v = make_float4(0.f, 0.f, 0.f, 0.f);
        if (node0 + row < n) v = *(const float4*)&hin[(size_t)(node0 + row) * HID + col];
        if (relu_in) {
            v.x = fmaxf(v.x, 0.f); v.y = fmaxf(v.y, 0.f);
            v.z = fmaxf(v.z, 0.f); v.w = fmaxf(v.w, 0.f);
        }
        *(float4*)&xs[row * 68 + col] = v;
    }
    __syncthreads();

    const int cx = t & 15;
    const int ny = t >> 4;
    float acc[4][4];
    const float4 bv = *(const float4*)&b[cx * 4];
    #pragma unroll
    for (int i = 0; i < 4; ++i) {
        acc[i][0] = bv.x; acc[i][1] = bv.y; acc[i][2] = bv.z; acc[i][3] = bv.w;
    }

    #pragma unroll 4
    for (int k4 = 0; k4 < 16; ++k4) {
        float4 xv[4];
        #pragma unroll
        for (int i = 0; i < 4; ++i)
            xv[i] = *(const float4*)&xs[(i * 16 + ny) * 68 + k4 * 4];
        #pragma unroll
        for (int kk = 0; kk < 4; ++kk) {
            float4 w = *(const float4*)&Ws[(k4 * 4 + kk) * HID + cx * 4];
            #pragma unroll
            for (int i = 0; i < 4; ++i) {
                float xval = reinterpret_cast<const float*>(&xv[i])[kk];
                acc[i][0] = fmaf(xval, w.x, acc[i][0]);
                acc[i][1] = fmaf(xval, w.y, acc[i][1]);
                acc[i][2] = fmaf(xval, w.z, acc[i][2]);
                acc[i][3] = fmaf(xval, w.w, acc[i][3]);
            }
        }
    }

    #pragma unroll
    for (int i = 0; i < 4; ++i) {
        const int node = node0 + i * 16 + ny;
        if (node < n) {
            float4 hv = make_float4(acc[i][0], acc[i][1], acc[i][2], acc[i][3]);
            *(float4*)&hout[(size_t)node * HID + cx * 4] = hv;
        }
    }
}

// ---------------- Gather (R8 exact): out[d] = Sum alpha * hl[src] ---------
__global__ __launch_bounds__(256) void k_gather(
    const int* __restrict__ rowptr, const int* __restrict__ csr_src,
    const float* __restrict__ alpha_csr, const float* __restrict__ hl,
    float* __restrict__ out, int n)
{
    const int wave = threadIdx.x >> 6;
    const int lane = threadIdx.x & 63;
    const int g    = lane >> 4;
    const int q    = lane & 15;
    const int node = blockIdx.x * 4 + wave;
    if (node >= n) return;

    const int p0 = rowptr[node], p1 = rowptr[node + 1];
    float4 acc = make_float4(0.f, 0.f, 0.f, 0.f);

    for (int base = p0; base < p1; base += 64) {
        int m = p1 - base; if (m > 64) m = 64;
        float a_l = 0.f; int s_l = 0;
        if (lane < m) { a_l = alpha_csr[base + lane]; s_l = csr_src[base + lane]; }
        for (int j = 0; j < m; j += 4) {
            const int e = j + g;
            float a = __shfl(a_l, e);
            int   s = __shfl(s_l, e);
            if (e < m) {
                float4 v = *(const float4*)&hl[(size_t)s * HID + q * 4];
                acc.x = fmaf(a, v.x, acc.x);
                acc.y = fmaf(a, v.y, acc.y);
                acc.z = fmaf(a, v.z, acc.z);
                acc.w = fmaf(a, v.w, acc.w);
            }
        }
    }
    #pragma unroll
    for (int m2 = 16; m2 <= 32; m2 <<= 1) {
        acc.x += __shfl_xor(acc.x, m2);
        acc.y += __shfl_xor(acc.y, m2);
        acc.z += __shfl_xor(acc.z, m2);
        acc.w += __shfl_xor(acc.w, m2);
    }
    if (g == 0)
        *(float4*)&out[(size_t)node * HID + q * 4] = acc;
}

// ---------------- Output GEMM 64x40 (R8 exact) ----------------
__global__ __launch_bounds__(256) void k_out_gemm(
    const float* __restrict__ hin, const float* __restrict__ W,
    const float* __restrict__ b, float* __restrict__ out, int n)
{
    __shared__ float xs[128 * 68];
    __shared__ float Ws[HID * 40];
    const int t = threadIdx.x;
    const int node0 = blockIdx.x * 128;

    #pragma unroll
    for (int p = 0; p < 3; ++p) {
        int c = t + p * 256;
        if (c < 640) *(float4*)&Ws[c * 4] = *(const float4*)&W[c * 4];
    }
    #pragma unroll
    for (int p = 0; p < 8; ++p) {
        int c = t + p * 256;
        int row = c >> 4;
        int col = (c & 15) * 4;
        float4 v = make_float4(0.f, 0.f, 0.f, 0.f);
        if (node0 + row < n) v = *(const float4*)&hin[(size_t)(node0 + row) * HID + col];
        v.x = fmaxf(v.x, 0.f); v.y = fmaxf(v.y, 0.f);
        v.z = fmaxf(v.z, 0.f); v.w = fmaxf(v.w, 0.f);
        *(float4*)&xs[row * 68 + col] = v;
    }
    __syncthreads();

    const int cx = t & 7;
    const int ny = t >> 3;
    float acc[4][5];
    #pragma unroll
    for (int j = 0; j < 5; ++j) {
        float bj = b[5 * cx + j];
        #pragma unroll
        for (int i = 0; i < 4; ++i) acc[i][j] = bj;
    }

    #pragma unroll 4
    for (int k4 = 0; k4 < 16; ++k4) {
        float4 xv[4];
        #pragma unroll
        for (int i = 0; i < 4; ++i)
            xv[i] = *(const float4*)&xs[(i * 32 + ny) * 68 + k4 * 4];
        #pragma unroll
        for (int kk = 0; kk < 4; ++kk) {
            int k = k4 * 4 + kk;
            float w[5];
            #pragma unroll
            for (int j = 0; j < 5; ++j) w[j] = Ws[k * 40 + 5 * cx + j];
            #pragma unroll
            for (int i = 0; i < 4; ++i) {
                float xval = reinterpret_cast<const float*>(&xv[i])[kk];
                #pragma unroll
                for (int j = 0; j < 5; ++j)
                    acc[i][j] = fmaf(xval, w[j], acc[i][j]);
            }
        }
    }

    #pragma unroll
    for (int i = 0; i < 4; ++i) {
        const int node = node0 + i * 32 + ny;
        if (node < n) {
            #pragma unroll
            for (int j = 0; j < 5; ++j)
                out[(size_t)node * 40 + 5 * cx + j] = acc[i][j];
        }
    }
}

extern "C" void kernel_launch(void* const* d_in, const int* in_sizes, int n_in,
                              void* d_out, int out_size, void* d_ws, size_t ws_size,
                              hipStream_t stream) {
    const float* x    = (const float*)d_in[0];
    const int*   ei   = (const int*)d_in[1];
    const float* Win  = (const float*)d_in[2];
    const float* bin  = (const float*)d_in[3];
    const float* wp   = (const float*)d_in[4];
    const float* attw = (const float*)d_in[5];
    const float* attb = (const float*)d_in[6];
    const float* Wout = (const float*)d_in[7];
    const float* bout = (const float*)d_in[8];
    const float* W0   = (const float*)d_in[9];
    const float* b0   = (const float*)d_in[10];
    const float* W1   = (const float*)d_in[11];
    const float* b1   = (const float*)d_in[12];
    const float* W2   = (const float*)d_in[13];
    const float* b2   = (const float*)d_in[14];

    const int N = in_sizes[0] / INC;
    const int E = in_sizes[1] / 2;
    const int* src = ei;
    const int* dst = ei + E;
    float* out = (float*)d_out;

    char* ws = (char*)d_ws;
    size_t off = 0;
    auto alloc = [&](size_t bytes) -> void* {
        void* p = ws + off;
        off = (off + bytes + 255) & ~(size_t)255;
        return p;
    };
    float* A        = (float*)alloc((size_t)N * HID * 4);
    float* Bf       = (float*)alloc((size_t)N * HID * 4);
    float* C        = (float*)alloc((size_t)N * HID * 4);
    float* delta    = (float*)alloc((size_t)N * 4);
    float* hwp      = (float*)alloc((size_t)N * 4);
    float* ai       = (float*)alloc((size_t)N * 4);
    float* aj       = (float*)alloc((size_t)N * 4);
    float* pi       = (float*)alloc((size_t)N * 4);
    int*   partials = (int*)alloc((size_t)NCHUNK * N * 4);
    int*   degtotal = (int*)alloc((size_t)N * 4);
    int*   rowptr   = (int*)alloc((size_t)(N + 1) * 4);
    int*   bsum     = (int*)alloc(256 * 4);
    int*   csr_eid  = (int*)alloc((size_t)E * 4);
    int*   csr_src  = (int*)alloc((size_t)E * 4);
    float* alpha    = (float*)alloc((size_t)E * 4);

    const int tileBlocks64  = (N + 63) / 64;          // 1563
    const int tileBlocks128 = (N + 127) / 128;
    const int nodeBlocks256 = (N + 255) / 256;
    const int nodeBlocksW   = (N + 3) / 4;
    const int scanBlocks    = (N + 1023) / 1024;      // 98

    const int psize = (N + NPART - 1) / NPART;        // 3125 (<= MAXP)
    const int fusedBlocks = NPART * NCHUNK + tileBlocks64;

    // ---- megakernel: LDS-histogram degree (512 blocks) || in_gemm ----
    k_ingemm_deg<<<fusedBlocks, 256, 0, stream>>>(
        x, Win, bin, wp, attw, A, delta, hwp, ai, aj, N,
        dst, partials, E, psize);

    // ---- chunk prefix + rowptr scans (exact int math) ----
    k_chunkprefix<<<nodeBlocks256, 256, 0, stream>>>(partials, degtotal, N);
    k_scan1<<<scanBlocks, 256, 0, stream>>>(degtotal, rowptr, bsum, N);
    k_scan2<<<1, 128, 0, stream>>>(bsum, scanBlocks);
    k_scan3<<<scanBlocks, 256, 0, stream>>>(rowptr, bsum, N, E);

    // ---- place (LDS cursor, no global atomics) + row sort ----
    k_place<<<NPART * NCHUNK, 256, 0, stream>>>(dst, rowptr, partials,
                                                csr_eid, E, N, psize);
    k_sortrow<<<NPART * 8, 256, 0, stream>>>(rowptr, csr_eid, src, csr_src,
                                             N, psize);

    // ---- attention ----
    k_neigh_pi<<<nodeBlocks256, 256, 0, stream>>>(rowptr, csr_src, delta, hwp, pi, N);
    k_att<<<nodeBlocks256, 256, 0, stream>>>(rowptr, csr_src, ai, aj, pi,
                                             attw, attb, alpha, N);

    // ---- layers (R8 exact) ----
    k_gemm64<<<tileBlocks64, 256, 0, stream>>>(A, W0, b0, Bf, N, 0);
    k_gather<<<nodeBlocksW, 256, 0, stream>>>(rowptr, csr_src, alpha, Bf, C, N);

    k_gemm64<<<tileBlocks64, 256, 0, stream>>>(C, W1, b1, A, N, 1);
    k_gather<<<nodeBlocksW, 256, 0, stream>>>(rowptr, csr_src, alpha, A, Bf, N);

    k_gemm64<<<tileBlocks64, 256, 0, stream>>>(Bf, W2, b2, C, N, 1);
    k_gather<<<nodeBlocksW, 256, 0, stream>>>(rowptr, csr_src, alpha, C, A, N);

    k_out_gemm<<<tileBlocks128, 256, 0, stream>>>(A, Wout, bout, out, N);
}